// Round 8
// baseline (62.949 us; speedup 1.0000x reference)
//
#include <hip/hip_runtime.h>

// pose_estimate_loss: trilinear SDF sample of a (128,64,64) f32 grid at N=4.19M
// points + Huber(delta=1) mean.
//
// R5 post-mortem: oct-table (1 gather/pt, bf16) regressed 26.4->~35us: MLP
// halved (4 vs 8 gathers in flight) in a gather-latency-bound regime.
// R6: proven f32 quad table (R3) + divide-free arithmetic + explicit 3-phase
// body guaranteeing 8 gathers in flight + nontemporal point-stream loads
// (keep the 8 MiB table L2-resident).

constexpr int THREADS = 256;   // 4 waves/block
constexpr int BLOCKS  = 2048;  // 8 blocks/CU; each thread: exactly 2 groups
constexpr int TBL_ENTRIES = 128 * 64 * 64;            // 524,288 float4s
constexpr size_t TBL_OFFSET = 16384;                  // partials live below
constexpr size_t WS_NEEDED  = TBL_OFFSET + (size_t)TBL_ENTRIES * 16;

typedef float f4v __attribute__((ext_vector_type(4)));

// Build packed quad table: t[x][y][z] = (v[y,z], v[y,z+1], v[y+1,z], v[y+1,z+1]),
// +1 clamped at 63 (bakes the reference's high-side clamp into the pack).
__global__ __launch_bounds__(THREADS) void build_table_kernel(
    const float* __restrict__ v, float4* __restrict__ t)
{
    int i = blockIdx.x * THREADS + threadIdx.x;       // one thread per entry
    int z = i & 63;
    int y = (i >> 6) & 63;
    int iz  = (z < 63) ? i + 1  : i;                  // (y, z+1)
    int iy  = (y < 63) ? i + 64 : i;                  // (y+1, z)
    int iyz = (z < 63) ? iy + 1 : iy;                 // (y+1, z+1)
    t[i] = make_float4(v[i], v[iz], v[iy], v[iyz]);
}

// Main: 2 gathers/point, 4 points/iter, explicit phases so all 8 gathers
// are independent and in flight together.
__global__ __launch_bounds__(THREADS) void sdf_quad_kernel(
    const float4* __restrict__ tbl,      // [128][64][64] quads
    const float*  __restrict__ pts,      // [N][3]
    const int*    __restrict__ hgt,      // scalar height_gt
    float* __restrict__ partials,        // [gridDim.x]
    int n)
{
    const float zsh = (float)hgt[0] * 5.0f;           // (height_gt/2)*10
    const int tid    = blockIdx.x * THREADS + threadIdx.x;
    const int stride = gridDim.x * THREADS;
    const int ngroups = n >> 2;

    float acc = 0.0f;
    for (int g = tid; g < ngroups; g += stride) {
        // 4 points = 12 floats = 3 x float4/lane, coalesced; nontemporal so the
        // read-once point stream doesn't evict the table from L2.
        const f4v* p4 = reinterpret_cast<const f4v*>(pts) + (size_t)g * 3;
        f4v A = __builtin_nontemporal_load(p4);
        f4v B = __builtin_nontemporal_load(p4 + 1);
        f4v C = __builtin_nontemporal_load(p4 + 2);
        float px[4] = {A.x, A.w, B.z, C.y};
        float py[4] = {A.y, B.x, B.w, C.z};
        float pz[4] = {A.z, B.y, C.x, C.w};

        // phase 1: weights + table indices for all 4 points (divide-free:
        // (p + off)/0.1 == p*10 + off*10; u = d - floor(d), diff vs ref <= ~2e-5)
        float UX[4], UY[4], UZ[4];
        int I0[4], I1[4];
#pragma unroll
        for (int i = 0; i < 4; ++i) {
            float dxc = fmaf(px[i], 10.0f, 60.0f);
            float dyc = fmaf(py[i], 10.0f, 30.0f);
            float dzc = fmaf(pz[i], 10.0f, zsh);
            float xm = floorf(dxc), ym = floorf(dyc), zm = floorf(dzc);
            float ux = dxc - xm, uy = dyc - ym, uz = dzc - zm;
            // pack bakes the clamped '+1' corner; low-side clamp (m<0) collapses
            // both ref corners to idx 0 == weight 0 on the '+1' corner
            uy = (ym < 0.0f) ? 0.0f : uy;
            uz = (zm < 0.0f) ? 0.0f : uz;
            int x0 = (int)fminf(fmaxf(xm,        0.0f), 127.0f);
            int x1 = (int)fminf(fmaxf(xm + 1.0f, 0.0f), 127.0f);
            int iy = (int)fminf(fmaxf(ym, 0.0f), 63.0f);
            int iz = (int)fminf(fmaxf(zm, 0.0f), 63.0f);
            int cell = (iy << 6) + iz;
            I0[i] = (x0 << 12) + cell;
            I1[i] = (x1 << 12) + cell;
            UX[i] = ux; UY[i] = uy; UZ[i] = uz;
        }
        // phase 2: issue all 8 independent gathers (MLP = 8)
        float4 Q0[4], Q1[4];
#pragma unroll
        for (int i = 0; i < 4; ++i) { Q0[i] = tbl[I0[i]]; Q1[i] = tbl[I1[i]]; }
        // phase 3: blend + Huber
#pragma unroll
        for (int i = 0; i < 4; ++i) {
            float uz = UZ[i], uy = UY[i], ux = UX[i];
            float a0 = fmaf(uz, Q0[i].y - Q0[i].x, Q0[i].x);   // y0 row: lerp z
            float a1 = fmaf(uz, Q0[i].w - Q0[i].z, Q0[i].z);   // y1 row
            float b0 = fmaf(uy, a1 - a0, a0);                  // x0 plane
            float c0 = fmaf(uz, Q1[i].y - Q1[i].x, Q1[i].x);
            float c1 = fmaf(uz, Q1[i].w - Q1[i].z, Q1[i].z);
            float b1 = fmaf(uy, c1 - c0, c0);                  // x1 plane
            float sdf = fmaf(ux, b1 - b0, b0);
            float a = fabsf(sdf);
            acc += (a < 1.0f) ? 0.5f * sdf * sdf : (a - 0.5f);
        }
    }

    // wave(64)-shuffle reduce + cross-wave LDS reduce
#pragma unroll
    for (int off = 32; off > 0; off >>= 1)
        acc += __shfl_down(acc, off);
    __shared__ float smem[THREADS / 64];
    if ((threadIdx.x & 63) == 0) smem[threadIdx.x >> 6] = acc;
    __syncthreads();
    if (threadIdx.x == 0) {
        float s = 0.0f;
#pragma unroll
        for (int w = 0; w < THREADS / 64; ++w) s += smem[w];
        partials[blockIdx.x] = s;
    }
}

// Fallback: direct 8-gather path (exact), used only if ws too small.
__global__ __launch_bounds__(THREADS) void sdf_direct_kernel(
    const float* __restrict__ voxels,
    const float* __restrict__ pts,
    const int*   __restrict__ hgt,
    float* __restrict__ partials,
    int n)
{
    const float zoff = (float)hgt[0] * 0.5f;
    const int tid    = blockIdx.x * THREADS + threadIdx.x;
    const int stride = gridDim.x * THREADS;
    const int ngroups = n >> 2;

    float acc = 0.0f;
    for (int g = tid; g < ngroups; g += stride) {
        const float4* p4 = reinterpret_cast<const float4*>(pts) + (size_t)g * 3;
        float4 A = p4[0];
        float4 B = p4[1];
        float4 C = p4[2];
        float px[4] = {A.x, A.w, B.z, C.y};
        float py[4] = {A.y, B.x, B.w, C.z};
        float pz[4] = {A.z, B.y, C.x, C.w};
#pragma unroll
        for (int i = 0; i < 4; ++i) {
            float x = px[i] + 6.0f;
            float y = py[i] + 3.0f;
            float z = pz[i] + zoff;
            float xm = floorf(x / 0.1f);
            float ym = floorf(y / 0.1f);
            float zm = floorf(z / 0.1f);
            float ux = (x - xm * 0.1f) / 0.1f;
            float uy = (y - ym * 0.1f) / 0.1f;
            float uz = (z - zm * 0.1f) / 0.1f;
            int x0 = (int)fminf(fmaxf(xm,        0.0f), 127.0f);
            int y0 = (int)fminf(fmaxf(ym,        0.0f),  63.0f);
            int z0 = (int)fminf(fmaxf(zm,        0.0f),  63.0f);
            int x1 = (int)fminf(fmaxf(xm + 1.0f, 0.0f), 127.0f);
            int y1 = (int)fminf(fmaxf(ym + 1.0f, 0.0f),  63.0f);
            int z1 = (int)fminf(fmaxf(zm + 1.0f, 0.0f),  63.0f);
            const int b00 = (x0 * 64 + y0) * 64;
            const int b01 = (x0 * 64 + y1) * 64;
            const int b10 = (x1 * 64 + y0) * 64;
            const int b11 = (x1 * 64 + y1) * 64;
            float v000 = voxels[b00 + z0];
            float v001 = voxels[b00 + z1];
            float v010 = voxels[b01 + z0];
            float v011 = voxels[b01 + z1];
            float v100 = voxels[b10 + z0];
            float v101 = voxels[b10 + z1];
            float v110 = voxels[b11 + z0];
            float v111 = voxels[b11 + z1];
            float wx1 = ux, wx0 = 1.0f - ux;
            float wy1 = uy, wy0 = 1.0f - uy;
            float wz1 = uz, wz0 = 1.0f - uz;
            float sdf =
                v111 * (wx1 * wy1 * wz1) + v110 * (wx1 * wy1 * wz0) +
                v101 * (wx1 * wy0 * wz1) + v100 * (wx1 * wy0 * wz0) +
                v011 * (wx0 * wy1 * wz1) + v010 * (wx0 * wy1 * wz0) +
                v001 * (wx0 * wy0 * wz1) + v000 * (wx0 * wy0 * wz0);
            float a = fabsf(sdf);
            acc += (a < 1.0f) ? 0.5f * sdf * sdf : (a - 0.5f);
        }
    }

#pragma unroll
    for (int off = 32; off > 0; off >>= 1)
        acc += __shfl_down(acc, off);
    __shared__ float smem[THREADS / 64];
    if ((threadIdx.x & 63) == 0) smem[threadIdx.x >> 6] = acc;
    __syncthreads();
    if (threadIdx.x == 0) {
        float s = 0.0f;
#pragma unroll
        for (int w = 0; w < THREADS / 64; ++w) s += smem[w];
        partials[blockIdx.x] = s;
    }
}

__global__ __launch_bounds__(THREADS) void reduce_kernel(
    const float* __restrict__ partials, float* __restrict__ out,
    int nparts, float inv_n)
{
    float acc = 0.0f;
    for (int i = threadIdx.x; i < nparts; i += THREADS) acc += partials[i];
#pragma unroll
    for (int off = 32; off > 0; off >>= 1)
        acc += __shfl_down(acc, off);
    __shared__ float smem[THREADS / 64];
    if ((threadIdx.x & 63) == 0) smem[threadIdx.x >> 6] = acc;
    __syncthreads();
    if (threadIdx.x == 0) {
        float s = 0.0f;
#pragma unroll
        for (int w = 0; w < THREADS / 64; ++w) s += smem[w];
        out[0] = s * inv_n;
    }
}

extern "C" void kernel_launch(void* const* d_in, const int* in_sizes, int n_in,
                              void* d_out, int out_size, void* d_ws, size_t ws_size,
                              hipStream_t stream) {
    const float* voxels = (const float*)d_in[0];   // (128,64,64) f32
    const float* pts    = (const float*)d_in[1];   // (N,3) f32
    const int*   hgt    = (const int*)d_in[2];     // scalar int
    float* out      = (float*)d_out;
    float* partials = (float*)d_ws;                // 2048 floats at ws head

    const int n = in_sizes[1] / 3;                 // 4,194,304

    if (ws_size >= WS_NEEDED) {
        float4* tbl = (float4*)((char*)d_ws + TBL_OFFSET);
        build_table_kernel<<<TBL_ENTRIES / THREADS, THREADS, 0, stream>>>(voxels, tbl);
        sdf_quad_kernel<<<BLOCKS, THREADS, 0, stream>>>(tbl, pts, hgt, partials, n);
    } else {
        sdf_direct_kernel<<<BLOCKS, THREADS, 0, stream>>>(voxels, pts, hgt, partials, n);
    }
    reduce_kernel<<<1, THREADS, 0, stream>>>(partials, out, BLOCKS, 1.0f / (float)n);
}

// Round 9
// 56.986 us; speedup vs baseline: 1.1046x; 1.1046x over previous
//
#include <hip/hip_runtime.h>

// pose_estimate_loss: trilinear SDF sample of a (128,64,64) f32 grid at N=4.19M
// points + Huber(delta=1) mean.
//
// R8 post-mortem: 3-phase restructure + nontemporal loads REGRESSED 26.4->53.9us
// (VGPR 36->24: compiler re-fused phases, killing MLP; nt hurt caching).
// R9: EXACT R3 structure (proven 26.4us main, MLP~8, VGPR 36) with ONE change:
// divide-free coords  d=fmaf(p,10,off); u=d-floor(d)  (kills 6 f32 divides/pt;
// diff vs ref <= ~2e-5 in u, continuous blend -> way under 2.9e-3 threshold).

constexpr int THREADS = 256;   // 4 waves/block
constexpr int BLOCKS  = 2048;  // 8 blocks/CU; grid-stride over N/4 groups
constexpr int TBL_ENTRIES = 128 * 64 * 64;            // 524,288 float4s
constexpr size_t TBL_OFFSET = 16384;                  // partials live below
constexpr size_t WS_NEEDED  = TBL_OFFSET + (size_t)TBL_ENTRIES * 16;

// Build packed quad table: t[x][y][z] = (v[y,z], v[y,z+1], v[y+1,z], v[y+1,z+1]),
// +1 clamped at 63 (bakes the reference's high-side clamp into the pack).
__global__ __launch_bounds__(THREADS) void build_table_kernel(
    const float* __restrict__ v, float4* __restrict__ t)
{
    int i = blockIdx.x * THREADS + threadIdx.x;       // one thread per entry
    int z = i & 63;
    int y = (i >> 6) & 63;
    int iz  = (z < 63) ? i + 1  : i;                  // (y, z+1)
    int iy  = (y < 63) ? i + 64 : i;                  // (y+1, z)
    int iyz = (z < 63) ? iy + 1 : iy;                 // (y+1, z+1)
    t[i] = make_float4(v[i], v[iz], v[iy], v[iyz]);
}

// Main: 2 gathers/point into the quad table.  R3-proven structure: per-point
// compute->load->blend, unrolled x4; compiler schedules loads with MLP~8.
__global__ __launch_bounds__(THREADS) void sdf_quad_kernel(
    const float4* __restrict__ tbl,      // [128][64][64] quads
    const float*  __restrict__ pts,      // [N][3]
    const int*    __restrict__ hgt,      // scalar height_gt
    float* __restrict__ partials,        // [gridDim.x]
    int n)
{
    const float zsh = (float)hgt[0] * 5.0f;           // (height_gt/2)*10
    const int tid    = blockIdx.x * THREADS + threadIdx.x;
    const int stride = gridDim.x * THREADS;
    const int ngroups = n >> 2;

    float acc = 0.0f;
    for (int g = tid; g < ngroups; g += stride) {
        // 4 points = 12 floats = 3 x float4/lane, coalesced
        const float4* p4 = reinterpret_cast<const float4*>(pts) + (size_t)g * 3;
        float4 A = p4[0];
        float4 B = p4[1];
        float4 C = p4[2];
        float px[4] = {A.x, A.w, B.z, C.y};
        float py[4] = {A.y, B.x, B.w, C.z};
        float pz[4] = {A.z, B.y, C.x, C.w};
#pragma unroll
        for (int i = 0; i < 4; ++i) {
            // divide-free: (p + off)/0.1 == p*10 + off*10; u = d - floor(d)
            float dxc = fmaf(px[i], 10.0f, 60.0f);
            float dyc = fmaf(py[i], 10.0f, 30.0f);
            float dzc = fmaf(pz[i], 10.0f, zsh);
            float xm = floorf(dxc), ym = floorf(dyc), zm = floorf(dzc);
            float ux = dxc - xm, uy = dyc - ym, uz = dzc - zm;
            // pack bakes the clamped '+1' corner; low-side clamp (m<0) collapses
            // both ref corners to idx 0 == weight 0 on the '+1' corner
            uy = (ym < 0.0f) ? 0.0f : uy;
            uz = (zm < 0.0f) ? 0.0f : uz;
            int x0 = (int)fminf(fmaxf(xm,        0.0f), 127.0f);
            int x1 = (int)fminf(fmaxf(xm + 1.0f, 0.0f), 127.0f);
            int iy = (int)fminf(fmaxf(ym, 0.0f), 63.0f);
            int iz = (int)fminf(fmaxf(zm, 0.0f), 63.0f);
            const int cell = (iy << 6) + iz;
            float4 q0 = tbl[(x0 << 12) + cell];        // x0 plane quad
            float4 q1 = tbl[(x1 << 12) + cell];        // x1 plane quad
            float wz0 = 1.0f - uz, wz1 = uz;
            float wy0 = 1.0f - uy, wy1 = uy;
            float b0 = wy0 * (q0.x * wz0 + q0.y * wz1) + wy1 * (q0.z * wz0 + q0.w * wz1);
            float b1 = wy0 * (q1.x * wz0 + q1.y * wz1) + wy1 * (q1.z * wz0 + q1.w * wz1);
            float sdf = (1.0f - ux) * b0 + ux * b1;
            float a = fabsf(sdf);
            acc += (a < 1.0f) ? 0.5f * sdf * sdf : (a - 0.5f);
        }
    }

    // wave(64)-shuffle reduce + cross-wave LDS reduce
#pragma unroll
    for (int off = 32; off > 0; off >>= 1)
        acc += __shfl_down(acc, off);
    __shared__ float smem[THREADS / 64];
    if ((threadIdx.x & 63) == 0) smem[threadIdx.x >> 6] = acc;
    __syncthreads();
    if (threadIdx.x == 0) {
        float s = 0.0f;
#pragma unroll
        for (int w = 0; w < THREADS / 64; ++w) s += smem[w];
        partials[blockIdx.x] = s;
    }
}

// Fallback: direct 8-gather path (exact), used only if ws too small.
__global__ __launch_bounds__(THREADS) void sdf_direct_kernel(
    const float* __restrict__ voxels,
    const float* __restrict__ pts,
    const int*   __restrict__ hgt,
    float* __restrict__ partials,
    int n)
{
    const float zoff = (float)hgt[0] * 0.5f;
    const int tid    = blockIdx.x * THREADS + threadIdx.x;
    const int stride = gridDim.x * THREADS;
    const int ngroups = n >> 2;

    float acc = 0.0f;
    for (int g = tid; g < ngroups; g += stride) {
        const float4* p4 = reinterpret_cast<const float4*>(pts) + (size_t)g * 3;
        float4 A = p4[0];
        float4 B = p4[1];
        float4 C = p4[2];
        float px[4] = {A.x, A.w, B.z, C.y};
        float py[4] = {A.y, B.x, B.w, C.z};
        float pz[4] = {A.z, B.y, C.x, C.w};
#pragma unroll
        for (int i = 0; i < 4; ++i) {
            float x = px[i] + 6.0f;
            float y = py[i] + 3.0f;
            float z = pz[i] + zoff;
            float xm = floorf(x / 0.1f);
            float ym = floorf(y / 0.1f);
            float zm = floorf(z / 0.1f);
            float ux = (x - xm * 0.1f) / 0.1f;
            float uy = (y - ym * 0.1f) / 0.1f;
            float uz = (z - zm * 0.1f) / 0.1f;
            int x0 = (int)fminf(fmaxf(xm,        0.0f), 127.0f);
            int y0 = (int)fminf(fmaxf(ym,        0.0f),  63.0f);
            int z0 = (int)fminf(fmaxf(zm,        0.0f),  63.0f);
            int x1 = (int)fminf(fmaxf(xm + 1.0f, 0.0f), 127.0f);
            int y1 = (int)fminf(fmaxf(ym + 1.0f, 0.0f),  63.0f);
            int z1 = (int)fminf(fmaxf(zm + 1.0f, 0.0f),  63.0f);
            const int b00 = (x0 * 64 + y0) * 64;
            const int b01 = (x0 * 64 + y1) * 64;
            const int b10 = (x1 * 64 + y0) * 64;
            const int b11 = (x1 * 64 + y1) * 64;
            float v000 = voxels[b00 + z0];
            float v001 = voxels[b00 + z1];
            float v010 = voxels[b01 + z0];
            float v011 = voxels[b01 + z1];
            float v100 = voxels[b10 + z0];
            float v101 = voxels[b10 + z1];
            float v110 = voxels[b11 + z0];
            float v111 = voxels[b11 + z1];
            float wx1 = ux, wx0 = 1.0f - ux;
            float wy1 = uy, wy0 = 1.0f - uy;
            float wz1 = uz, wz0 = 1.0f - uz;
            float sdf =
                v111 * (wx1 * wy1 * wz1) + v110 * (wx1 * wy1 * wz0) +
                v101 * (wx1 * wy0 * wz1) + v100 * (wx1 * wy0 * wz0) +
                v011 * (wx0 * wy1 * wz1) + v010 * (wx0 * wy1 * wz0) +
                v001 * (wx0 * wy0 * wz1) + v000 * (wx0 * wy0 * wz0);
            float a = fabsf(sdf);
            acc += (a < 1.0f) ? 0.5f * sdf * sdf : (a - 0.5f);
        }
    }

#pragma unroll
    for (int off = 32; off > 0; off >>= 1)
        acc += __shfl_down(acc, off);
    __shared__ float smem[THREADS / 64];
    if ((threadIdx.x & 63) == 0) smem[threadIdx.x >> 6] = acc;
    __syncthreads();
    if (threadIdx.x == 0) {
        float s = 0.0f;
#pragma unroll
        for (int w = 0; w < THREADS / 64; ++w) s += smem[w];
        partials[blockIdx.x] = s;
    }
}

__global__ __launch_bounds__(THREADS) void reduce_kernel(
    const float* __restrict__ partials, float* __restrict__ out,
    int nparts, float inv_n)
{
    float acc = 0.0f;
    for (int i = threadIdx.x; i < nparts; i += THREADS) acc += partials[i];
#pragma unroll
    for (int off = 32; off > 0; off >>= 1)
        acc += __shfl_down(acc, off);
    __shared__ float smem[THREADS / 64];
    if ((threadIdx.x & 63) == 0) smem[threadIdx.x >> 6] = acc;
    __syncthreads();
    if (threadIdx.x == 0) {
        float s = 0.0f;
#pragma unroll
        for (int w = 0; w < THREADS / 64; ++w) s += smem[w];
        out[0] = s * inv_n;
    }
}

extern "C" void kernel_launch(void* const* d_in, const int* in_sizes, int n_in,
                              void* d_out, int out_size, void* d_ws, size_t ws_size,
                              hipStream_t stream) {
    const float* voxels = (const float*)d_in[0];   // (128,64,64) f32
    const float* pts    = (const float*)d_in[1];   // (N,3) f32
    const int*   hgt    = (const int*)d_in[2];     // scalar int
    float* out      = (float*)d_out;
    float* partials = (float*)d_ws;                // 2048 floats at ws head

    const int n = in_sizes[1] / 3;                 // 4,194,304

    if (ws_size >= WS_NEEDED) {
        float4* tbl = (float4*)((char*)d_ws + TBL_OFFSET);
        build_table_kernel<<<TBL_ENTRIES / THREADS, THREADS, 0, stream>>>(voxels, tbl);
        sdf_quad_kernel<<<BLOCKS, THREADS, 0, stream>>>(tbl, pts, hgt, partials, n);
    } else {
        sdf_direct_kernel<<<BLOCKS, THREADS, 0, stream>>>(voxels, pts, hgt, partials, n);
    }
    reduce_kernel<<<1, THREADS, 0, stream>>>(partials, out, BLOCKS, 1.0f / (float)n);
}

// Round 10
// 56.538 us; speedup vs baseline: 1.1134x; 1.0079x over previous
//
#include <hip/hip_runtime.h>

// pose_estimate_loss: trilinear SDF sample of a (128,64,64) f32 grid at N=4.19M
// points + Huber(delta=1) mean.
//
// R9 post-mortem: divide-free math dropped VGPR 36->20; allocator reused regs
// for gathers -> waitcnt per point -> MLP ~2 -> 50us (VALU 10%, HBM 10%:
// pure latency stall). R3's divides were accidentally forcing the good
// schedule.  R10: force it deliberately -- 3-phase body with
// sched_barrier(0) between the 8 gathers and the blends, so all 8 loads'
// results are live across the barrier (MLP=8 by construction).

constexpr int THREADS = 256;   // 4 waves/block
constexpr int BLOCKS  = 2048;  // 8 blocks/CU; grid-stride over N/4 groups
constexpr int TBL_ENTRIES = 128 * 64 * 64;            // 524,288 float4s
constexpr size_t TBL_OFFSET = 16384;                  // partials live below
constexpr size_t WS_NEEDED  = TBL_OFFSET + (size_t)TBL_ENTRIES * 16;

// Build packed quad table: t[x][y][z] = (v[y,z], v[y,z+1], v[y+1,z], v[y+1,z+1]),
// +1 clamped at 63 (bakes the reference's high-side clamp into the pack).
__global__ __launch_bounds__(THREADS) void build_table_kernel(
    const float* __restrict__ v, float4* __restrict__ t)
{
    int i = blockIdx.x * THREADS + threadIdx.x;       // one thread per entry
    int z = i & 63;
    int y = (i >> 6) & 63;
    int iz  = (z < 63) ? i + 1  : i;                  // (y, z+1)
    int iy  = (y < 63) ? i + 64 : i;                  // (y+1, z)
    int iyz = (z < 63) ? iy + 1 : iy;                 // (y+1, z+1)
    t[i] = make_float4(v[i], v[iz], v[iy], v[iyz]);
}

// Main: 2 gathers/point, 4 points/iter; sched_barrier pins loads-before-blends.
__global__ __launch_bounds__(THREADS) void sdf_quad_kernel(
    const float4* __restrict__ tbl,      // [128][64][64] quads
    const float*  __restrict__ pts,      // [N][3]
    const int*    __restrict__ hgt,      // scalar height_gt
    float* __restrict__ partials,        // [gridDim.x]
    int n)
{
    const float zsh = (float)hgt[0] * 5.0f;           // (height_gt/2)*10
    const int tid    = blockIdx.x * THREADS + threadIdx.x;
    const int stride = gridDim.x * THREADS;
    const int ngroups = n >> 2;

    float acc = 0.0f;
    for (int g = tid; g < ngroups; g += stride) {
        // 4 points = 12 floats = 3 x float4/lane, coalesced
        const float4* p4 = reinterpret_cast<const float4*>(pts) + (size_t)g * 3;
        float4 A = p4[0];
        float4 B = p4[1];
        float4 C = p4[2];
        float px[4] = {A.x, A.w, B.z, C.y};
        float py[4] = {A.y, B.x, B.w, C.z};
        float pz[4] = {A.z, B.y, C.x, C.w};

        // phase 1: weights + indices for all 4 points (divide-free:
        // (p+off)/0.1 == p*10 + off*10; u = d - floor(d); R9 absmax was 0.0)
        float UX[4], UY[4], UZ[4];
        int I0[4], I1[4];
#pragma unroll
        for (int i = 0; i < 4; ++i) {
            float dxc = fmaf(px[i], 10.0f, 60.0f);
            float dyc = fmaf(py[i], 10.0f, 30.0f);
            float dzc = fmaf(pz[i], 10.0f, zsh);
            float xm = floorf(dxc), ym = floorf(dyc), zm = floorf(dzc);
            float ux = dxc - xm, uy = dyc - ym, uz = dzc - zm;
            // pack bakes the clamped '+1' corner; low-side clamp (m<0) collapses
            // both ref corners to idx 0 == weight 0 on the '+1' corner
            uy = (ym < 0.0f) ? 0.0f : uy;
            uz = (zm < 0.0f) ? 0.0f : uz;
            int x0 = (int)fminf(fmaxf(xm,        0.0f), 127.0f);
            int x1 = (int)fminf(fmaxf(xm + 1.0f, 0.0f), 127.0f);
            int iy = (int)fminf(fmaxf(ym, 0.0f), 63.0f);
            int iz = (int)fminf(fmaxf(zm, 0.0f), 63.0f);
            int cell = (iy << 6) + iz;
            I0[i] = (x0 << 12) + cell;
            I1[i] = (x1 << 12) + cell;
            UX[i] = ux; UY[i] = uy; UZ[i] = uz;
        }

        // phase 2: all 8 independent gathers issued back-to-back
        float4 Q0[4], Q1[4];
#pragma unroll
        for (int i = 0; i < 4; ++i) { Q0[i] = tbl[I0[i]]; Q1[i] = tbl[I1[i]]; }

        // pin the schedule: no blend may hoist above, no load may sink below.
        // All 8 float4 results live across this point -> MLP=8 enforced.
        __builtin_amdgcn_sched_barrier(0);

        // phase 3: blend + Huber
#pragma unroll
        for (int i = 0; i < 4; ++i) {
            float uz = UZ[i], uy = UY[i], ux = UX[i];
            float wz0 = 1.0f - uz, wz1 = uz;
            float wy0 = 1.0f - uy, wy1 = uy;
            float b0 = wy0 * (Q0[i].x * wz0 + Q0[i].y * wz1)
                     + wy1 * (Q0[i].z * wz0 + Q0[i].w * wz1);
            float b1 = wy0 * (Q1[i].x * wz0 + Q1[i].y * wz1)
                     + wy1 * (Q1[i].z * wz0 + Q1[i].w * wz1);
            float sdf = (1.0f - ux) * b0 + ux * b1;
            float a = fabsf(sdf);
            acc += (a < 1.0f) ? 0.5f * sdf * sdf : (a - 0.5f);
        }
    }

    // wave(64)-shuffle reduce + cross-wave LDS reduce
#pragma unroll
    for (int off = 32; off > 0; off >>= 1)
        acc += __shfl_down(acc, off);
    __shared__ float smem[THREADS / 64];
    if ((threadIdx.x & 63) == 0) smem[threadIdx.x >> 6] = acc;
    __syncthreads();
    if (threadIdx.x == 0) {
        float s = 0.0f;
#pragma unroll
        for (int w = 0; w < THREADS / 64; ++w) s += smem[w];
        partials[blockIdx.x] = s;
    }
}

// Fallback: direct 8-gather path (exact), used only if ws too small.
__global__ __launch_bounds__(THREADS) void sdf_direct_kernel(
    const float* __restrict__ voxels,
    const float* __restrict__ pts,
    const int*   __restrict__ hgt,
    float* __restrict__ partials,
    int n)
{
    const float zoff = (float)hgt[0] * 0.5f;
    const int tid    = blockIdx.x * THREADS + threadIdx.x;
    const int stride = gridDim.x * THREADS;
    const int ngroups = n >> 2;

    float acc = 0.0f;
    for (int g = tid; g < ngroups; g += stride) {
        const float4* p4 = reinterpret_cast<const float4*>(pts) + (size_t)g * 3;
        float4 A = p4[0];
        float4 B = p4[1];
        float4 C = p4[2];
        float px[4] = {A.x, A.w, B.z, C.y};
        float py[4] = {A.y, B.x, B.w, C.z};
        float pz[4] = {A.z, B.y, C.x, C.w};
#pragma unroll
        for (int i = 0; i < 4; ++i) {
            float x = px[i] + 6.0f;
            float y = py[i] + 3.0f;
            float z = pz[i] + zoff;
            float xm = floorf(x / 0.1f);
            float ym = floorf(y / 0.1f);
            float zm = floorf(z / 0.1f);
            float ux = (x - xm * 0.1f) / 0.1f;
            float uy = (y - ym * 0.1f) / 0.1f;
            float uz = (z - zm * 0.1f) / 0.1f;
            int x0 = (int)fminf(fmaxf(xm,        0.0f), 127.0f);
            int y0 = (int)fminf(fmaxf(ym,        0.0f),  63.0f);
            int z0 = (int)fminf(fmaxf(zm,        0.0f),  63.0f);
            int x1 = (int)fminf(fmaxf(xm + 1.0f, 0.0f), 127.0f);
            int y1 = (int)fminf(fmaxf(ym + 1.0f, 0.0f),  63.0f);
            int z1 = (int)fminf(fmaxf(zm + 1.0f, 0.0f),  63.0f);
            const int b00 = (x0 * 64 + y0) * 64;
            const int b01 = (x0 * 64 + y1) * 64;
            const int b10 = (x1 * 64 + y0) * 64;
            const int b11 = (x1 * 64 + y1) * 64;
            float v000 = voxels[b00 + z0];
            float v001 = voxels[b00 + z1];
            float v010 = voxels[b01 + z0];
            float v011 = voxels[b01 + z1];
            float v100 = voxels[b10 + z0];
            float v101 = voxels[b10 + z1];
            float v110 = voxels[b11 + z0];
            float v111 = voxels[b11 + z1];
            float wx1 = ux, wx0 = 1.0f - ux;
            float wy1 = uy, wy0 = 1.0f - uy;
            float wz1 = uz, wz0 = 1.0f - uz;
            float sdf =
                v111 * (wx1 * wy1 * wz1) + v110 * (wx1 * wy1 * wz0) +
                v101 * (wx1 * wy0 * wz1) + v100 * (wx1 * wy0 * wz0) +
                v011 * (wx0 * wy1 * wz1) + v010 * (wx0 * wy1 * wz0) +
                v001 * (wx0 * wy0 * wz1) + v000 * (wx0 * wy0 * wz0);
            float a = fabsf(sdf);
            acc += (a < 1.0f) ? 0.5f * sdf * sdf : (a - 0.5f);
        }
    }

#pragma unroll
    for (int off = 32; off > 0; off >>= 1)
        acc += __shfl_down(acc, off);
    __shared__ float smem[THREADS / 64];
    if ((threadIdx.x & 63) == 0) smem[threadIdx.x >> 6] = acc;
    __syncthreads();
    if (threadIdx.x == 0) {
        float s = 0.0f;
#pragma unroll
        for (int w = 0; w < THREADS / 64; ++w) s += smem[w];
        partials[blockIdx.x] = s;
    }
}

__global__ __launch_bounds__(THREADS) void reduce_kernel(
    const float* __restrict__ partials, float* __restrict__ out,
    int nparts, float inv_n)
{
    float acc = 0.0f;
    for (int i = threadIdx.x; i < nparts; i += THREADS) acc += partials[i];
#pragma unroll
    for (int off = 32; off > 0; off >>= 1)
        acc += __shfl_down(acc, off);
    __shared__ float smem[THREADS / 64];
    if ((threadIdx.x & 63) == 0) smem[threadIdx.x >> 6] = acc;
    __syncthreads();
    if (threadIdx.x == 0) {
        float s = 0.0f;
#pragma unroll
        for (int w = 0; w < THREADS / 64; ++w) s += smem[w];
        out[0] = s * inv_n;
    }
}

extern "C" void kernel_launch(void* const* d_in, const int* in_sizes, int n_in,
                              void* d_out, int out_size, void* d_ws, size_t ws_size,
                              hipStream_t stream) {
    const float* voxels = (const float*)d_in[0];   // (128,64,64) f32
    const float* pts    = (const float*)d_in[1];   // (N,3) f32
    const int*   hgt    = (const int*)d_in[2];     // scalar int
    float* out      = (float*)d_out;
    float* partials = (float*)d_ws;                // 2048 floats at ws head

    const int n = in_sizes[1] / 3;                 // 4,194,304

    if (ws_size >= WS_NEEDED) {
        float4* tbl = (float4*)((char*)d_ws + TBL_OFFSET);
        build_table_kernel<<<TBL_ENTRIES / THREADS, THREADS, 0, stream>>>(voxels, tbl);
        sdf_quad_kernel<<<BLOCKS, THREADS, 0, stream>>>(tbl, pts, hgt, partials, n);
    } else {
        sdf_direct_kernel<<<BLOCKS, THREADS, 0, stream>>>(voxels, pts, hgt, partials, n);
    }
    reduce_kernel<<<1, THREADS, 0, stream>>>(partials, out, BLOCKS, 1.0f / (float)n);
}